// Round 1
// 165.005 us; speedup vs baseline: 1.0001x; 1.0001x over previous
//
#include <hip/hip_runtime.h>

// HybridSymmetricLoss: B=65536, T=3, J=10 (fp32).
// loss = min over 6 perms of mean BCE(assign[b,perm], labels) + category BCE
// under the argmin perm.  Logs in log2 space (clip -100/ln2), one ln2 scale
// at the end.
//
// R8 = R7 with the cross-lane reduction restructured:
//  - reduce 6 per-perm partials instead of 9 e[tl][ta] partials
//    (the sum-of-log1p term S1 is perm-independent, so fold it per-lane);
//  - butterfly over basis {1,2,7,15,16}: stages 1/2/7/15 are full-rate
//    DPP VALU adds (quad_perm 0xB1 / 0x4E, row_half_mirror 0x141,
//    row_mirror 0x140); only xor-16 uses the DS pipe.
//    DS ops per wave: 45 -> 6.
// Carrier otherwise identical: one b per 32-lane half-wave, lanes 0..24
// hold 4 jk via float4, non-temporal loads on the two 78.6 MB arrays,
// two-pass final sum via d_ws.

#define CLIP2 (-144.26950408889634f)   // -100 / ln(2)
#define LN2   (0.6931471805599453f)

typedef float vfloat4 __attribute__((ext_vector_type(4)));

template<int CTRL>
__device__ __forceinline__ float dpp_xor_add(float x) {
    // butterfly stage: x + (x shuffled by a DPP lane permutation)
    int y = __builtin_amdgcn_update_dpp(0, __float_as_int(x), CTRL, 0xF, 0xF, true);
    return x + __int_as_float(y);
}

__launch_bounds__(256)
__global__ void hybrid_pass1(const float* __restrict__ assign,
                             const float* __restrict__ cat,
                             const float* __restrict__ assign_lab,
                             const float* __restrict__ cat_lab,
                             float* __restrict__ ws, int B) {
    const int sub = threadIdx.x & 31;               // lane within half-wave
    const int b   = (blockIdx.x * blockDim.x + threadIdx.x) >> 5;
    if (b >= B) return;

    const bool act = sub < 25;                      // 25 lanes * 4 = 100 jk

    // q[p] = per-lane partial of the perm-p log-sum (to be max'ed over p)
    float q[6] = {0.f, 0.f, 0.f, 0.f, 0.f, 0.f};

    if (act) {
        const vfloat4* Ab = (const vfloat4*)(assign     + (size_t)b * 300 + sub * 4);
        const vfloat4* Yb = (const vfloat4*)(assign_lab + (size_t)b * 300 + sub * 4);
        vfloat4 av[3], yv[3];
        #pragma unroll
        for (int t = 0; t < 3; ++t) {
            av[t] = __builtin_nontemporal_load(Ab + t * 25);   // +100 floats
            yv[t] = __builtin_nontemporal_load(Yb + t * 25);
        }

        float d[3][4];
        float S1 = 0.f;                      // sum of log1m terms, perm-independent
        #pragma unroll
        for (int t = 0; t < 3; ++t) {
            #pragma unroll
            for (int c = 0; c < 4; ++c) {
                float a  = av[t][c];
                float lp = fmaxf(__log2f(a),        CLIP2);
                float l1 = fmaxf(__log2f(1.0f - a), CLIP2);
                d[t][c] = lp - l1;
                S1 += l1;
            }
        }
        float dot[3][3];
        #pragma unroll
        for (int tl = 0; tl < 3; ++tl) {
            #pragma unroll
            for (int ta = 0; ta < 3; ++ta) {
                float acc = 0.f;
                #pragma unroll
                for (int c = 0; c < 4; ++c)
                    acc = fmaf(yv[tl][c], d[ta][c], acc);
                dot[tl][ta] = acc;
            }
        }
        const int P0[6] = {0,0,1,1,2,2};
        const int P1[6] = {1,2,0,2,0,1};
        const int P2[6] = {2,1,2,0,1,0};
        #pragma unroll
        for (int p = 0; p < 6; ++p)
            q[p] = S1 + dot[0][P0[p]] + dot[1][P1[p]] + dot[2][P2[p]];
    }

    // category prefetch so its latency overlaps the butterfly
    float cb0=0.f,cb1=0.f,cb2=0.f,gb0=0.f,gb1=0.f,gb2=0.f;
    if (sub == 0) {
        const float* cp = cat     + (size_t)b * 3;
        const float* gp = cat_lab + (size_t)b * 3;
        cb0 = cp[0]; cb1 = cp[1]; cb2 = cp[2];
        gb0 = gp[0]; gb1 = gp[1]; gb2 = gp[2];
    }

    // 5-stage butterfly within each 32-lane half over GF(2) basis
    // {1,2,7,15,16}: four DPP VALU stages + one ds_swizzle stage.
    #pragma unroll
    for (int p = 0; p < 6; ++p) q[p] = dpp_xor_add<0xB1>(q[p]);   // xor 1 (quad_perm 1,0,3,2)
    #pragma unroll
    for (int p = 0; p < 6; ++p) q[p] = dpp_xor_add<0x4E>(q[p]);   // xor 2 (quad_perm 2,3,0,1)
    #pragma unroll
    for (int p = 0; p < 6; ++p) q[p] = dpp_xor_add<0x141>(q[p]);  // xor 7 (row_half_mirror)
    #pragma unroll
    for (int p = 0; p < 6; ++p) q[p] = dpp_xor_add<0x140>(q[p]);  // xor 15 (row_mirror)
    #pragma unroll
    for (int p = 0; p < 6; ++p) q[p] += __shfl_xor(q[p], 16, 64); // xor 16 (DS)

    float lsum = 0.f;
    if (sub == 0) {
        // min over perms of C = -ln2*q  ==  max over perms of q
        const int P0[6] = {0,0,1,1,2,2};
        const int P1[6] = {1,2,0,2,0,1};
        const int P2[6] = {2,1,2,0,1,0};
        float best = q[0];
        int bp0 = 0, bp1 = 1, bp2 = 2;
        #pragma unroll
        for (int p = 1; p < 6; ++p) {
            if (q[p] > best) { best = q[p]; bp0 = P0[p]; bp1 = P1[p]; bp2 = P2[p]; }
        }

        float lp0 = fmaxf(__log2f(cb0), CLIP2), l10 = fmaxf(__log2f(1.f-cb0), CLIP2);
        float lp1 = fmaxf(__log2f(cb1), CLIP2), l11 = fmaxf(__log2f(1.f-cb1), CLIP2);
        float lp2 = fmaxf(__log2f(cb2), CLIP2), l12 = fmaxf(__log2f(1.f-cb2), CLIP2);

        float lpa = (bp0==0)?lp0:((bp0==1)?lp1:lp2);
        float l1a = (bp0==0)?l10:((bp0==1)?l11:l12);
        float lpb = (bp1==0)?lp0:((bp1==1)?lp1:lp2);
        float l1b = (bp1==0)?l10:((bp1==1)?l11:l12);
        float lpc = (bp2==0)?lp0:((bp2==1)?lp1:lp2);
        float l1c = (bp2==0)?l10:((bp2==1)?l11:l12);

        float csum = -(gb0*lpa + (1.f-gb0)*l1a
                     + gb1*lpb + (1.f-gb1)*l1b
                     + gb2*lpc + (1.f-gb2)*l1c);

        lsum = best * (-1.f/300.f) + csum * (1.f/3.f);
    }

    // block reduce: 8 half-wave leaders per 256-thread block
    __shared__ float sred[8];
    if (sub == 0) sred[threadIdx.x >> 5] = lsum;
    __syncthreads();
    if (threadIdx.x == 0) {
        float s = 0.f;
        #pragma unroll
        for (int i = 0; i < 8; ++i) s += sred[i];
        ws[blockIdx.x] = s * (LN2 / (float)B);
    }
}

__launch_bounds__(1024)
__global__ void hybrid_pass2(const float* __restrict__ ws,
                             float* __restrict__ out, int n) {
    float s = 0.f;
    for (int i = threadIdx.x; i < n; i += 1024) s += ws[i];
    #pragma unroll
    for (int off = 32; off > 0; off >>= 1) s += __shfl_xor(s, off, 64);
    __shared__ float sm[16];
    if ((threadIdx.x & 63) == 0) sm[threadIdx.x >> 6] = s;
    __syncthreads();
    if (threadIdx.x == 0) {
        float t = 0.f;
        #pragma unroll
        for (int i = 0; i < 16; ++i) t += sm[i];
        out[0] = t;
    }
}

extern "C" void kernel_launch(void* const* d_in, const int* in_sizes, int n_in,
                              void* d_out, int out_size, void* d_ws, size_t ws_size,
                              hipStream_t stream) {
    const float* assign     = (const float*)d_in[0];
    const float* cat        = (const float*)d_in[1];
    const float* assign_lab = (const float*)d_in[2];
    const float* cat_lab    = (const float*)d_in[3];
    float* out = (float*)d_out;
    float* ws  = (float*)d_ws;

    const int B = in_sizes[0] / 300;               // T*J*J = 300
    const int blocks = (B * 32 + 255) / 256;       // one b per 32-lane half

    hybrid_pass1<<<blocks, 256, 0, stream>>>(assign, cat, assign_lab,
                                             cat_lab, ws, B);
    hybrid_pass2<<<1, 1024, 0, stream>>>(ws, out, blocks);
}